// Round 1
// baseline (640.431 us; speedup 1.0000x reference)
//
#include <hip/hip_runtime.h>

// Conv2dInt8 R4: single fused kernel, ZERO workspace use.
//   x(8,32,512,512) fp32 -> quantize int8 into padded NHWC LDS tile (10 rows x 68 cols x 32ch)
//   weights OIHW int32 -> packed int8 LDS [kh*2+pair][cout][64] (K=64 = 2 kw-taps x 32 cin)
//   one barrier, then exact int32 conv via mfma_i32_16x16x64_i8 (identical math/epilogue to R3).
// Rationale: R3's 3-dispatch pipeline ran at ~5x the memory roofline (~106us floor vs 527us).
// Fusing removes the 135MB xq round-trip, two dispatch drains, and all d_ws usage
// (harness re-poisons the 1GiB workspace every iteration).

#define N_IMG 8
#define CIN   32
#define COUT  32
#define HD    512
#define WD    512
#define TH    8
#define TW    64
#define XROWS 10
#define XCOLS 68

typedef int intx4 __attribute__((ext_vector_type(4)));

__global__ __launch_bounds__(256, 3) void conv8_fused(const float* __restrict__ x,
                                                      const int* __restrict__ wq,
                                                      const int* __restrict__ bias,
                                                      float* __restrict__ out)
{
    __shared__ alignas(16) unsigned char xs[XROWS * XCOLS * CIN];  // 21760 B
    __shared__ alignas(16) char wp[6 * 32 * 64];                   // 12288 B

    const int tid = threadIdx.x;
    const int bx = blockIdx.x;   // w tile (64 px)
    const int by = blockIdx.y;   // h tile (8 rows)
    const int n  = blockIdx.z;

    // ---- stage weights: OIHW int32 -> int8 wp[(kh*2+pair)*32+cout][sel*32+cin] ----
    // kw = pair*2 + sel; kw==3 slots are zero (pair 1 is half-dead, K-padding).
    for (int i = tid; i < 6 * 32 * 64; i += 256) {
        const int row  = i >> 6;
        const int k    = i & 63;
        const int khp  = row >> 5;
        const int cout = row & 31;
        const int kh   = khp >> 1;
        const int pr   = khp & 1;
        const int sel  = k >> 5;
        const int cin  = k & 31;
        const int kw   = pr * 2 + sel;
        int v = 0;
        if (kw < 3) v = wq[((cout * CIN + cin) * 3 + kh) * 3 + kw] - 128;  // OIHW
        wp[i] = (char)v;
    }

    // ---- stage input: quantize fp32 NCHW -> int8 NHWC tile in LDS ----
    // tile covers h = by*8-1 .. by*8+8 (10 rows), w = bx*64-1 .. bx*64+66 (68 cols).
    // i-order: half-major, then row, then pc -> consecutive lanes read consecutive w (coalesced).
    const int h0  = by * TH - 1;
    const int wt0 = bx * TW - 1;
    for (int i = tid; i < 2 * XROWS * XCOLS; i += 256) {
        const int half = i / (XROWS * XCOLS);
        const int rem  = i - half * (XROWS * XCOLS);
        const int row  = rem / XCOLS;
        const int pc   = rem - row * XCOLS;
        const int h = h0 + row;
        const int w = wt0 + pc;
        unsigned int pk[4] = {0u, 0u, 0u, 0u};
        if ((unsigned)h < (unsigned)HD && (unsigned)w < (unsigned)WD) {
            const float* xp = x + ((size_t)(n * CIN + half * 16) * HD + h) * WD + w;
#pragma unroll
            for (int c4 = 0; c4 < 4; ++c4) {
                unsigned int b[4];
#pragma unroll
                for (int j = 0; j < 4; ++j) {
                    float xv = xp[(size_t)(c4 * 4 + j) * (HD * WD)];
                    float q = rintf(xv / 0.05f);                  // identical numerics to R3 (passed)
                    q = fminf(fmaxf(q, -128.0f), 127.0f);
                    b[j] = (unsigned int)(int)q & 0xffu;
                }
                pk[c4] = b[0] | (b[1] << 8) | (b[2] << 16) | (b[3] << 24);
            }
        }
        *(uint4*)(xs + (size_t)(row * XCOLS + pc) * CIN + half * 16) =
            make_uint4(pk[0], pk[1], pk[2], pk[3]);
    }

    __syncthreads();

    // ---- compute: identical structure to R3's conv8_kernel, B-frags from LDS ----
    const int lane = tid & 63;
    const int wave = tid >> 6;
    const int l15  = lane & 15;
    const int quad = lane >> 4;

    // A-frags (weights): m=cout=l15(+hf*16), k-group=quad (16 int8/lane)
    intx4 Af[3][2][2];
#pragma unroll
    for (int kh = 0; kh < 3; ++kh)
#pragma unroll
        for (int p = 0; p < 2; ++p)
#pragma unroll
            for (int hf = 0; hf < 2; ++hf)
                Af[kh][p][hf] = *(const intx4*)(wp + (((kh * 2 + p) * 32 + hf * 16 + l15) << 6) + quad * 16);

    int bi0[4], bi1[4];
#pragma unroll
    for (int r = 0; r < 4; ++r) { bi0[r] = bias[quad * 4 + r]; bi1[r] = bias[16 + quad * 4 + r]; }

    const int wseg = wave * 16;  // this wave's 16 output pixels (block-relative): wseg + l15
    // output pixel W(block-rel) needs input cols W-1..W+1 -> LDS pc = W..W+2; pair p spans pc W+2p..W+2p+1.
    const unsigned char* bbase = xs + (size_t)(wseg + l15) * CIN + quad * 16;

#pragma unroll
    for (int it = 0; it < 4; ++it) {
        // rolling 4-row window: output rows 2it, 2it+1 use LDS rows 2it .. 2it+3
        intx4 Bw[4][2];
#pragma unroll
        for (int r = 0; r < 4; ++r)
#pragma unroll
            for (int p = 0; p < 2; ++p)
                Bw[r][p] = *(const intx4*)(bbase + (size_t)((2 * it + r) * XCOLS) * CIN + p * 64);

        intx4 acc[2][2];
#pragma unroll
        for (int o = 0; o < 2; ++o)
#pragma unroll
            for (int hf = 0; hf < 2; ++hf)
                acc[o][hf] = (intx4){0, 0, 0, 0};

#pragma unroll
        for (int o = 0; o < 2; ++o)
#pragma unroll
            for (int kh = 0; kh < 3; ++kh)
#pragma unroll
                for (int p = 0; p < 2; ++p) {
                    const intx4 b = Bw[o + kh][p];
                    acc[o][0] = __builtin_amdgcn_mfma_i32_16x16x64_i8(Af[kh][p][0], b, acc[o][0], 0, 0, 0);
                    acc[o][1] = __builtin_amdgcn_mfma_i32_16x16x64_i8(Af[kh][p][1], b, acc[o][1], 0, 0, 0);
                }

        // epilogue: D col(n=pixel)=l15, row(m=cout)=quad*4+r -> 16-lane contiguous stores
#pragma unroll
        for (int o = 0; o < 2; ++o) {
            const int h = by * TH + 2 * it + o;
            float* op0 = out + (((size_t)n * COUT + quad * 4) * HD + h) * WD + bx * TW + wseg + l15;
            float* op1 = op0 + (size_t)16 * HD * WD;
#pragma unroll
            for (int r = 0; r < 4; ++r) {
                int v0 = acc[o][0][r] + bi0[r];              // exact y_int
                float yq0 = rintf((float)v0 * 0.01f);
                yq0 = fminf(fmaxf(yq0, -127.f), 127.f);
                op0[(size_t)r * (HD * WD)] = fmaxf(yq0 * 0.1f, 0.f);
                int v1 = acc[o][1][r] + bi1[r];
                float yq1 = rintf((float)v1 * 0.01f);
                yq1 = fminf(fmaxf(yq1, -127.f), 127.f);
                op1[(size_t)r * (HD * WD)] = fmaxf(yq1 * 0.1f, 0.f);
            }
        }
    }
}

extern "C" void kernel_launch(void* const* d_in, const int* in_sizes, int n_in,
                              void* d_out, int out_size, void* d_ws, size_t ws_size,
                              hipStream_t stream) {
    const float* x  = (const float*)d_in[0];
    const int*   wq = (const int*)d_in[1];
    const int*   bi = (const int*)d_in[2];
    float* out = (float*)d_out;
    (void)d_ws; (void)ws_size;

    conv8_fused<<<dim3(WD / TW, HD / TH, N_IMG), dim3(256), 0, stream>>>(x, wq, bi, out);
}

// Round 2
// 495.909 us; speedup vs baseline: 1.2914x; 1.2914x over previous
//
#include <hip/hip_runtime.h>

// Conv2dInt8 R5: fused kernel, staging rebuilt for memory-level parallelism.
// R4 post-mortem: traffic near-ideal (314+262 MB) but only 22% HBM BW; per-CU in-flight
// ~2.6KB (~1 load/wave) -> latency-bound staging. Fixes:
//  (1) depth-2 register double-buffer in quant staging: issue task k+1's 16 loads
//      before packing task k (compiler emits counted vmcnt -> 16-32 outstanding/wave)
//  (2) __launch_bounds__(256,4): 4 blocks/CU (LDS 34KB*4=137KB fits) -> 16 waves/CU
//  (3) weight staging dword-granular, 12 uniform unrolled iters (was 48 serial byte iters)
// Compute + epilogue identical to R4 (exact int32 MFMA, passed absmax 0.25).

#define N_IMG 8
#define CIN   32
#define COUT  32
#define HD    512
#define WD    512
#define TH    8
#define TW    64
#define XROWS 10
#define XCOLS 68
#define NTASK (2 * XROWS * XCOLS)   // 1360 staging tasks, 16 channels each

typedef int intx4 __attribute__((ext_vector_type(4)));

__global__ __launch_bounds__(256, 4) void conv8_fused(const float* __restrict__ x,
                                                      const int* __restrict__ wq,
                                                      const int* __restrict__ bias,
                                                      float* __restrict__ out)
{
    __shared__ alignas(16) unsigned char xs[XROWS * XCOLS * CIN];  // 21760 B
    __shared__ alignas(16) char wp[6 * 32 * 64];                   // 12288 B

    const int tid = threadIdx.x;
    const int bx = blockIdx.x;   // w tile (64 px)
    const int by = blockIdx.y;   // h tile (8 rows)
    const int n  = blockIdx.z;

    // ---- stage weights: dword-granular, uniform 12 iters/thread, batched loads ----
    // wp[(kh*2+pair)*32+cout][sel*32+cin], kw = pair*2+sel; kw==3 slots zero.
#pragma unroll
    for (int k = 0; k < 12; ++k) {
        const int d    = tid + k * 256;   // dword index, 12288/4 = 3072 total
        const int row  = d >> 4;          // 16 dwords per 64B row
        const int k0   = (d & 15) * 4;    // first byte-lane k within row
        const int khp  = row >> 5;
        const int cout = row & 31;
        const int kh   = khp >> 1;
        const int pr   = khp & 1;
        const int sel  = k0 >> 5;         // uniform across the 4 bytes of this dword
        const int kw   = pr * 2 + sel;
        unsigned int pk = 0u;
        if (kw < 3) {
            const int cin0 = k0 & 31;
            const int* wqp = wq + ((cout * CIN + cin0) * 3 + kh) * 3 + kw;  // OIHW, cin stride 9
            unsigned int b0 = (unsigned int)(wqp[0]  - 128) & 0xffu;
            unsigned int b1 = (unsigned int)(wqp[9]  - 128) & 0xffu;
            unsigned int b2 = (unsigned int)(wqp[18] - 128) & 0xffu;
            unsigned int b3 = (unsigned int)(wqp[27] - 128) & 0xffu;
            pk = b0 | (b1 << 8) | (b2 << 16) | (b3 << 24);
        }
        *(unsigned int*)(wp + d * 4) = pk;
    }

    // ---- stage input: quantize fp32 NCHW -> int8 NHWC LDS tile, depth-2 pipelined ----
    const int h0  = by * TH - 1;
    const int wt0 = bx * TW - 1;

    float bufA[16], bufB[16];

    auto issue = [&](int k, float (&buf)[16]) {
        const int idx = tid + k * 256;
        if (idx >= NTASK) return;
        const int half = (idx >= XROWS * XCOLS) ? 1 : 0;
        const int rem  = idx - half * (XROWS * XCOLS);
        const int row  = rem / XCOLS;
        const int pc   = rem - row * XCOLS;
        const int h = h0 + row, w = wt0 + pc;
        if ((unsigned)h < (unsigned)HD && (unsigned)w < (unsigned)WD) {
            const float* xp = x + ((size_t)(n * CIN + half * 16) * HD + h) * WD + w;
#pragma unroll
            for (int c = 0; c < 16; ++c)
                buf[c] = xp[(size_t)c * (HD * WD)];   // 16 independent strided loads
        }
    };
    auto flush = [&](int k, float (&buf)[16]) {
        const int idx = tid + k * 256;
        if (idx >= NTASK) return;
        const int half = (idx >= XROWS * XCOLS) ? 1 : 0;
        const int rem  = idx - half * (XROWS * XCOLS);
        const int row  = rem / XCOLS;
        const int pc   = rem - row * XCOLS;
        const int h = h0 + row, w = wt0 + pc;
        const bool inb = (unsigned)h < (unsigned)HD && (unsigned)w < (unsigned)WD;
        unsigned int pk[4] = {0u, 0u, 0u, 0u};
        if (inb) {
#pragma unroll
            for (int c4 = 0; c4 < 4; ++c4) {
                unsigned int b[4];
#pragma unroll
                for (int j = 0; j < 4; ++j) {
                    float q = rintf(buf[c4 * 4 + j] / 0.05f);   // identical numerics (passed)
                    q = fminf(fmaxf(q, -128.0f), 127.0f);
                    b[j] = (unsigned int)(int)q & 0xffu;
                }
                pk[c4] = b[0] | (b[1] << 8) | (b[2] << 16) | (b[3] << 24);
            }
        }
        *(uint4*)(xs + (size_t)(row * XCOLS + pc) * CIN + half * 16) =
            make_uint4(pk[0], pk[1], pk[2], pk[3]);
    };

    // 1360 tasks / 256 threads = 6 pipeline stages (last partially predicated)
    issue(0, bufA);
    issue(1, bufB); flush(0, bufA);
    issue(2, bufA); flush(1, bufB);
    issue(3, bufB); flush(2, bufA);
    issue(4, bufA); flush(3, bufB);
    issue(5, bufB); flush(4, bufA);
    flush(5, bufB);

    __syncthreads();

    // ---- compute: identical to R4 ----
    const int lane = tid & 63;
    const int wave = tid >> 6;
    const int l15  = lane & 15;
    const int quad = lane >> 4;

    intx4 Af[3][2][2];
#pragma unroll
    for (int kh = 0; kh < 3; ++kh)
#pragma unroll
        for (int p = 0; p < 2; ++p)
#pragma unroll
            for (int hf = 0; hf < 2; ++hf)
                Af[kh][p][hf] = *(const intx4*)(wp + (((kh * 2 + p) * 32 + hf * 16 + l15) << 6) + quad * 16);

    int bi0[4], bi1[4];
#pragma unroll
    for (int r = 0; r < 4; ++r) { bi0[r] = bias[quad * 4 + r]; bi1[r] = bias[16 + quad * 4 + r]; }

    const int wseg = wave * 16;
    const unsigned char* bbase = xs + (size_t)(wseg + l15) * CIN + quad * 16;

#pragma unroll
    for (int it = 0; it < 4; ++it) {
        intx4 Bw[4][2];
#pragma unroll
        for (int r = 0; r < 4; ++r)
#pragma unroll
            for (int p = 0; p < 2; ++p)
                Bw[r][p] = *(const intx4*)(bbase + (size_t)((2 * it + r) * XCOLS) * CIN + p * 64);

        intx4 acc[2][2];
#pragma unroll
        for (int o = 0; o < 2; ++o)
#pragma unroll
            for (int hf = 0; hf < 2; ++hf)
                acc[o][hf] = (intx4){0, 0, 0, 0};

#pragma unroll
        for (int o = 0; o < 2; ++o)
#pragma unroll
            for (int kh = 0; kh < 3; ++kh)
#pragma unroll
                for (int p = 0; p < 2; ++p) {
                    const intx4 b = Bw[o + kh][p];
                    acc[o][0] = __builtin_amdgcn_mfma_i32_16x16x64_i8(Af[kh][p][0], b, acc[o][0], 0, 0, 0);
                    acc[o][1] = __builtin_amdgcn_mfma_i32_16x16x64_i8(Af[kh][p][1], b, acc[o][1], 0, 0, 0);
                }

#pragma unroll
        for (int o = 0; o < 2; ++o) {
            const int h = by * TH + 2 * it + o;
            float* op0 = out + (((size_t)n * COUT + quad * 4) * HD + h) * WD + bx * TW + wseg + l15;
            float* op1 = op0 + (size_t)16 * HD * WD;
#pragma unroll
            for (int r = 0; r < 4; ++r) {
                int v0 = acc[o][0][r] + bi0[r];
                float yq0 = rintf((float)v0 * 0.01f);
                yq0 = fminf(fmaxf(yq0, -127.f), 127.f);
                op0[(size_t)r * (HD * WD)] = fmaxf(yq0 * 0.1f, 0.f);
                int v1 = acc[o][1][r] + bi1[r];
                float yq1 = rintf((float)v1 * 0.01f);
                yq1 = fminf(fmaxf(yq1, -127.f), 127.f);
                op1[(size_t)r * (HD * WD)] = fmaxf(yq1 * 0.1f, 0.f);
            }
        }
    }
}

extern "C" void kernel_launch(void* const* d_in, const int* in_sizes, int n_in,
                              void* d_out, int out_size, void* d_ws, size_t ws_size,
                              hipStream_t stream) {
    const float* x  = (const float*)d_in[0];
    const int*   wq = (const int*)d_in[1];
    const int*   bi = (const int*)d_in[2];
    float* out = (float*)d_out;
    (void)d_ws; (void)ws_size;

    conv8_fused<<<dim3(WD / TW, HD / TH, N_IMG), dim3(256), 0, stream>>>(x, wq, bi, out);
}

// Round 4
// 483.985 us; speedup vs baseline: 1.3232x; 1.0246x over previous
//
#include <hip/hip_runtime.h>

// Conv2dInt8 R7 (= R6 resubmit; round-3 bench died on container acquire, no kernel verdict).
// Fused kernel; staging rebuilt around float4 loads + sched_barrier.
// R5 post-mortem: depth-2 scalar pipeline got only 2.5 TB/s (32%); VGPR=56 shows the
// compiler never kept the double-buffer live -> ~1 outstanding load/wave. Fixes:
//  (1) core staging loads are float4 (4 px x 16 ch per task): 1KB/wave per instruction,
//      16 outstanding = 16KB/wave in flight regardless of scheduler mood
//  (2) __builtin_amdgcn_sched_barrier(0) pins the 16-load batch before the quant/pack
//  (3) LDS int8 tile split into two 16-ch planes [half][pix][16]: ds_write_b128 staging
//      (conflict-free) and contiguous ds_read_b128 B-frags (kills 1.48M bank conflicts).
//      k-permutation identical (k = quad*16+j -> sel=quad>>1, cin=(quad&1)*16+j for BOTH
//      A and B) -> A-pack/MFMA unchanged.
// Compute + epilogue numerics identical to R4/R5 (exact int32 MFMA, passed absmax 0.25).

#define N_IMG 8
#define CIN   32
#define COUT  32
#define HD    512
#define WD    512
#define TH    8
#define TW    64
#define XROWS 10
#define XCOLS 68
#define PLANE (XROWS * XCOLS * 16)   // 10880 B per 16-channel plane

typedef int intx4 __attribute__((ext_vector_type(4)));
typedef float floatx4 __attribute__((ext_vector_type(4)));

__global__ __launch_bounds__(256, 4) void conv8_fused(const float* __restrict__ x,
                                                      const int* __restrict__ wq,
                                                      const int* __restrict__ bias,
                                                      float* __restrict__ out)
{
    __shared__ alignas(16) unsigned char xs[2 * PLANE];   // 21760 B
    __shared__ alignas(16) char wp[6 * 32 * 64];          // 12288 B

    const int tid = threadIdx.x;
    const int bx = blockIdx.x;   // w tile (64 px)
    const int by = blockIdx.y;   // h tile (8 rows)
    const int n  = blockIdx.z;

    // ---- stage weights (dword-granular, 12 uniform iters) ----
#pragma unroll
    for (int k = 0; k < 12; ++k) {
        const int d    = tid + k * 256;
        const int row  = d >> 4;
        const int k0   = (d & 15) * 4;
        const int khp  = row >> 5;
        const int cout = row & 31;
        const int kh   = khp >> 1;
        const int pr   = khp & 1;
        const int sel  = k0 >> 5;
        const int kw   = pr * 2 + sel;
        unsigned int pk = 0u;
        if (kw < 3) {
            const int cin0 = k0 & 31;
            const int* wqp = wq + ((cout * CIN + cin0) * 3 + kh) * 3 + kw;
            unsigned int b0 = (unsigned int)(wqp[0]  - 128) & 0xffu;
            unsigned int b1 = (unsigned int)(wqp[9]  - 128) & 0xffu;
            unsigned int b2 = (unsigned int)(wqp[18] - 128) & 0xffu;
            unsigned int b3 = (unsigned int)(wqp[27] - 128) & 0xffu;
            pk = b0 | (b1 << 8) | (b2 << 16) | (b3 << 24);
        }
        *(unsigned int*)(wp + d * 4) = pk;
    }

    // ---- stage input: fp32 NCHW -> int8 [half][pix][16] LDS planes ----
    // core tasks (t<320): (row, half, g) -> float4 covering w = bx*64 + 4g .. +3 (aligned),
    //   16 channels -> 16 float4 loads, pack 4 pixels x 16ch, 4x ds_write_b128.
    // halo tasks (t>=320): pc in {0,65} scalar columns. pc 66/67 only feed the zero
    //   kw=3 tap (weights are 0) -> left uninitialized on purpose.
    const int h0 = by * TH - 1;
    for (int t = tid; t < 360; t += 256) {
        if (t < 320) {
            const int g    = t & 15;
            const int half = (t >> 4) & 1;
            const int row  = t >> 5;
            const int h    = h0 + row;
            const bool inb = (unsigned)h < (unsigned)HD;
            floatx4 v[16];
            if (inb) {
                const float* xp = x + ((size_t)(n * CIN + half * 16) * HD + h) * WD + bx * TW + g * 4;
#pragma unroll
                for (int c = 0; c < 16; ++c)
                    v[c] = *(const floatx4*)(xp + (size_t)c * (HD * WD));
            }
            __builtin_amdgcn_sched_barrier(0);   // keep the 16-load batch issued together
            unsigned char* dst = xs + half * PLANE + ((size_t)row * XCOLS + 1 + g * 4) * 16;
#pragma unroll
            for (int j = 0; j < 4; ++j) {        // pixel within the float4
                unsigned int pk[4] = {0u, 0u, 0u, 0u};
                if (inb) {
#pragma unroll
                    for (int c4 = 0; c4 < 4; ++c4) {
                        unsigned int bb = 0u;
#pragma unroll
                        for (int cc = 0; cc < 4; ++cc) {
                            float q = rintf(v[c4 * 4 + cc][j] / 0.05f);   // identical numerics
                            q = fminf(fmaxf(q, -128.0f), 127.0f);
                            bb |= ((unsigned int)(int)q & 0xffu) << (cc * 8);
                        }
                        pk[c4] = bb;
                    }
                }
                *(uint4*)(dst + j * 16) = make_uint4(pk[0], pk[1], pk[2], pk[3]);
            }
        } else {
            const int u    = t - 320;            // 0..39
            const int pc   = (u & 1) ? 65 : 0;
            const int half = (u >> 1) & 1;
            const int row  = u >> 2;
            const int h    = h0 + row;
            const int w    = bx * TW - 1 + pc;
            const bool inb = (unsigned)h < (unsigned)HD && (unsigned)w < (unsigned)WD;
            float v[16];
            if (inb) {
                const float* xp = x + ((size_t)(n * CIN + half * 16) * HD + h) * WD + w;
#pragma unroll
                for (int c = 0; c < 16; ++c)
                    v[c] = xp[(size_t)c * (HD * WD)];
            }
            __builtin_amdgcn_sched_barrier(0);
            unsigned int pk[4] = {0u, 0u, 0u, 0u};
            if (inb) {
#pragma unroll
                for (int c4 = 0; c4 < 4; ++c4) {
                    unsigned int bb = 0u;
#pragma unroll
                    for (int cc = 0; cc < 4; ++cc) {
                        float q = rintf(v[c4 * 4 + cc] / 0.05f);
                        q = fminf(fmaxf(q, -128.0f), 127.0f);
                        bb |= ((unsigned int)(int)q & 0xffu) << (cc * 8);
                    }
                    pk[c4] = bb;
                }
            }
            *(uint4*)(xs + half * PLANE + ((size_t)row * XCOLS + pc) * 16) =
                make_uint4(pk[0], pk[1], pk[2], pk[3]);
        }
    }

    __syncthreads();

    // ---- compute: same MFMA plan; B-frags from the split-plane layout ----
    const int lane = tid & 63;
    const int wave = tid >> 6;
    const int l15  = lane & 15;
    const int quad = lane >> 4;

    intx4 Af[3][2][2];
#pragma unroll
    for (int kh = 0; kh < 3; ++kh)
#pragma unroll
        for (int p = 0; p < 2; ++p)
#pragma unroll
            for (int hf = 0; hf < 2; ++hf)
                Af[kh][p][hf] = *(const intx4*)(wp + (((kh * 2 + p) * 32 + hf * 16 + l15) << 6) + quad * 16);

    int bi0[4], bi1[4];
#pragma unroll
    for (int r = 0; r < 4; ++r) { bi0[r] = bias[quad * 4 + r]; bi1[r] = bias[16 + quad * 4 + r]; }

    const int wseg = wave * 16;
    // k = quad*16 + j -> kw-sel = quad>>1 (pixel offset), ch-half = quad&1 (plane), cin = (quad&1)*16 + j
    const unsigned char* bbase = xs + (size_t)(quad & 1) * PLANE
                               + ((size_t)(wseg + l15 + (quad >> 1))) * 16;

#pragma unroll
    for (int it = 0; it < 4; ++it) {
        intx4 Bw[4][2];
#pragma unroll
        for (int r = 0; r < 4; ++r)
#pragma unroll
            for (int p = 0; p < 2; ++p)
                Bw[r][p] = *(const intx4*)(bbase + (size_t)((2 * it + r) * XCOLS + 2 * p) * 16);

        intx4 acc[2][2];
#pragma unroll
        for (int o = 0; o < 2; ++o)
#pragma unroll
            for (int hf = 0; hf < 2; ++hf)
                acc[o][hf] = (intx4){0, 0, 0, 0};

#pragma unroll
        for (int o = 0; o < 2; ++o)
#pragma unroll
            for (int kh = 0; kh < 3; ++kh)
#pragma unroll
                for (int p = 0; p < 2; ++p) {
                    const intx4 b = Bw[o + kh][p];
                    acc[o][0] = __builtin_amdgcn_mfma_i32_16x16x64_i8(Af[kh][p][0], b, acc[o][0], 0, 0, 0);
                    acc[o][1] = __builtin_amdgcn_mfma_i32_16x16x64_i8(Af[kh][p][1], b, acc[o][1], 0, 0, 0);
                }

#pragma unroll
        for (int o = 0; o < 2; ++o) {
            const int h = by * TH + 2 * it + o;
            float* op0 = out + (((size_t)n * COUT + quad * 4) * HD + h) * WD + bx * TW + wseg + l15;
            float* op1 = op0 + (size_t)16 * HD * WD;
#pragma unroll
            for (int r = 0; r < 4; ++r) {
                int v0 = acc[o][0][r] + bi0[r];
                float yq0 = rintf((float)v0 * 0.01f);
                yq0 = fminf(fmaxf(yq0, -127.f), 127.f);
                op0[(size_t)r * (HD * WD)] = fmaxf(yq0 * 0.1f, 0.f);
                int v1 = acc[o][1][r] + bi1[r];
                float yq1 = rintf((float)v1 * 0.01f);
                yq1 = fminf(fmaxf(yq1, -127.f), 127.f);
                op1[(size_t)r * (HD * WD)] = fmaxf(yq1 * 0.1f, 0.f);
            }
        }
    }
}

extern "C" void kernel_launch(void* const* d_in, const int* in_sizes, int n_in,
                              void* d_out, int out_size, void* d_ws, size_t ws_size,
                              hipStream_t stream) {
    const float* x  = (const float*)d_in[0];
    const int*   wq = (const int*)d_in[1];
    const int*   bi = (const int*)d_in[2];
    float* out = (float*)d_out;
    (void)d_ws; (void)ws_size;

    conv8_fused<<<dim3(WD / TW, HD / TH, N_IMG), dim3(256), 0, stream>>>(x, wq, bi, out);
}